// Round 6
// baseline (10.220 us; speedup 1.0000x reference)
//
#include <hip/hip_runtime.h>

// DirectionalConv2D: 5x5 wind-directional Gaussian blur, f32. B=4, H=W=512.
// w_ij = A^{ai^2} * B^{aj^2} * g^{ai*aj}; A=exp(-I c^2), B=exp(-I s^2), g=exp(-2 I c s)
// I = 1/(2*sigma^2) = 1/4.5; c,s = normalized (u+1e-8, v). B = exp(-I)/A.
// R6: 2 px/thread -> 8192 waves -> 8 waves/SIMD (full residency) for latency hiding,
// WITH LDS row staging so live VGPR state fits the 64-reg cap (R4 spilled because it
// held 15 float2 rows in registers; here rows are consumed row-by-row from LDS).
// One block = one image row (512 px). Stage 5 halo rows, zero pads -> no masks.

constexpr int Wd = 512;
constexpr int Hd = 512;
constexpr int PW = 520;   // 4 pad + 512 + 4 pad

__global__ __launch_bounds__(256, 8) void dirconv_kernel(
    const float* __restrict__ fire,
    const float* __restrict__ wu,
    const float* __restrict__ wv,
    float* __restrict__ out)
{
    constexpr float C1 = -0.3205988979753274f;   // -log2(e)/4.5
    constexpr float C2 = -0.6411977959506548f;   // -2*log2(e)/4.5
    constexpr float KB = 0.8007374029168082f;    // exp(-1/4.5)

    __shared__ float lds[5][PW];                 // 10,400 B

    const int blk = blockIdx.x;                  // 0..2047
    const int b   = blk >> 9;                    // image index
    const int y0  = blk & 511;                   // output row
    const int t   = threadIdx.x;
    const float* img = fire + (b << 18);

    const int x = t << 1;                        // 2 px per thread, even
    const int p = (b << 18) + (y0 << 9) + x;

    // ---- per-pixel u,v loads first (coeff deps) ----
    float2 u2 = *reinterpret_cast<const float2*>(wu + p);
    float2 v2 = *reinterpret_cast<const float2*>(wv + p);

    // ---- zero side pads: 5 rows x 2 sides ----
    if (t < 10) {
        int r = t >> 1, sd = t & 1;
        *reinterpret_cast<float4*>(&lds[r][sd ? 516 : 0]) =
            make_float4(0.f, 0.f, 0.f, 0.f);
    }
    // ---- cooperative stage: 5 rows x 128 float4 = 640 tasks ----
#pragma unroll
    for (int j = 0; j < 3; ++j) {
        int id = t + (j << 8);                   // 0..767, last loop partial
        if (id < 640) {
            int r  = id >> 7;                    // staged row 0..4
            int q  = id & 127;                   // float4 index in row
            int gr = y0 - 2 + r;                 // global image row
            float4 val = make_float4(0.f, 0.f, 0.f, 0.f);
            if ((unsigned)gr < (unsigned)Hd)     // wave-uniform
                val = *reinterpret_cast<const float4*>(img + (gr << 9) + (q << 2));
            *reinterpret_cast<float4*>(&lds[r][4 + (q << 2)]) = val;
        }
    }

    // ---- per-pixel coefficients (overlaps staging loads in flight) ----
    float ua[2] = {u2.x, u2.y};
    float va[2] = {v2.x, v2.y};

    float A1[2], A4[2], B1a[2], B4a[2], WsA[2], S[2];
    float c1[2], c2[2], c3[2], c4[2], d1[2], d2[2], d3[2], d4[2];

#pragma unroll
    for (int k = 0; k < 2; ++k) {
        float un = ua[k] + 1e-8f;
        float vv = va[k];
        float r2 = fmaf(un, un, vv * vv);
        r2 = fmaxf(r2, 1e-36f);
        float ir = __builtin_amdgcn_rsqf(r2);
        float c = un * ir;
        float s = vv * ir;
        float a1 = exp2f(c * c * C1);              // A = exp(-I c^2)
        float g  = exp2f(c * s * C2);              // g = exp(-2 I c s)
        float b1 = KB * __builtin_amdgcn_rcpf(a1); // B = exp(-I)/A
        float a2 = a1 * a1;  float A4v = a2 * a2;
        float b2 = b1 * b1;  float B4v = b2 * b2;
        float gi  = __builtin_amdgcn_rcpf(g);
        float g2 = g * g,   gi2 = gi * gi;
        float g4 = g2 * g2, gi4 = gi2 * gi2;
        c1[k] = b1 * g;  c2[k] = b1 * gi;  c3[k] = B4v * g2;  c4[k] = B4v * gi2;
        d1[k] = b1 * g2; d2[k] = b1 * gi2; d3[k] = B4v * g4;  d4[k] = B4v * gi4;
        A1[k] = a1; A4[k] = A4v; B1a[k] = b1; B4a[k] = B4v;
        float sc = 1.0f + ((c1[k] + c2[k]) + (c3[k] + c4[k]));
        float sd = 1.0f + ((d1[k] + d2[k]) + (d3[k] + d4[k]));
        float base = fmaf(2.0f, b1 + B4v, 1.0f);
        WsA[k] = fmaf(2.0f, fmaf(a1, sc, A4v * sd), base);
        S[k] = 0.0f;
    }

    __syncthreads();

    // ---- accumulate 5 window rows from LDS (pads/OOB rows are zeros) ----
    // lds col c holds global col c-4; window = global x-2..x+3 -> lds x+2..x+7
    float fc0 = 0.f, fc1 = 0.f;                  // fire at center (residual)
#pragma unroll
    for (int di = 0; di < 5; ++di) {
        const int ai = di - 2;
        float2 a = *reinterpret_cast<const float2*>(&lds[di][x + 2]);
        float2 m = *reinterpret_cast<const float2*>(&lds[di][x + 4]);
        float2 r2v = *reinterpret_cast<const float2*>(&lds[di][x + 6]);
        if (di == 2) { fc0 = m.x; fc1 = m.y; }
        float fv[6] = {a.x, a.y, m.x, m.y, r2v.x, r2v.y};
#pragma unroll
        for (int k = 0; k < 2; ++k) {
            float fm2 = fv[k], fm1 = fv[k + 1], f0 = fv[k + 2];
            float fp1 = fv[k + 3], fp2 = fv[k + 4];
            if (ai == 0) {
                float R = fmaf(B4a[k], fm2 + fp2, fmaf(B1a[k], fm1 + fp1, f0));
                S[k] += R;
            } else if (ai == 1) {
                float R = fmaf(c4[k], fm2, fmaf(c2[k], fm1,
                          fmaf(c1[k], fp1, fmaf(c3[k], fp2, f0))));
                S[k] = fmaf(A1[k], R, S[k]);
            } else if (ai == -1) {
                float R = fmaf(c3[k], fm2, fmaf(c1[k], fm1,
                          fmaf(c2[k], fp1, fmaf(c4[k], fp2, f0))));
                S[k] = fmaf(A1[k], R, S[k]);
            } else if (ai == 2) {
                float R = fmaf(d4[k], fm2, fmaf(d2[k], fm1,
                          fmaf(d1[k], fp1, fmaf(d3[k], fp2, f0))));
                S[k] = fmaf(A4[k], R, S[k]);
            } else { // ai == -2
                float R = fmaf(d3[k], fm2, fmaf(d1[k], fm1,
                          fmaf(d2[k], fp1, fmaf(d4[k], fp2, f0))));
                S[k] = fmaf(A4[k], R, S[k]);
            }
        }
    }

    float2 o;
    float fca[2] = {fc0, fc1};
#pragma unroll
    for (int k = 0; k < 2; ++k) {
        float inv = __builtin_amdgcn_rcpf(WsA[k] + 1e-8f);
        float sp = S[k] * inv;
        float r = fmaf(0.7f, sp, 0.3f * fca[k]);
        r = fminf(fmaxf(r, 0.0f), 1.0f);
        (&o.x)[k] = r;
    }
    *reinterpret_cast<float2*>(out + p) = o;
}

extern "C" void kernel_launch(void* const* d_in, const int* in_sizes, int n_in,
                              void* d_out, int out_size, void* d_ws, size_t ws_size,
                              hipStream_t stream) {
    const float* fire = (const float*)d_in[0];
    const float* wu   = (const float*)d_in[1];
    const float* wv   = (const float*)d_in[2];
    float* out        = (float*)d_out;
    // B*H*W = 1048576 px; one block per image row (512 px, 2 px/thread)
    int blocks = out_size >> 9;               // 2048
    dirconv_kernel<<<blocks, 256, 0, stream>>>(fire, wu, wv, out);
}